// Round 5
// baseline (428.233 us; speedup 1.0000x reference)
//
#include <hip/hip_runtime.h>
#include <hip/hip_fp16.h>
#include <stdint.h>

typedef unsigned int   uint32;
typedef unsigned short ushort_t;
typedef _Float16 half8   __attribute__((ext_vector_type(8)));
typedef float    floatx4 __attribute__((ext_vector_type(4)));

#define DEVINL __device__ __forceinline__

#define HSTR 264   // h buffer stride (256 + 8 pad), multiple of 8 for 16B-aligned b128
#define XSTR 72    // xyz-posenc stride (64 + 8 pad)
#define DSTR 40    // dir-posenc stride (32 + 8 pad)
#define N_FRAGS 1172            // total 1KB weight fragments

// Packed f16 weight fragments in module-owned device memory (d_ws is too small;
// round-1 showed OOB d_ws writes corrupt the harness's pristine copies).
// prep_weights rewrites this every launch from the restored fp32 inputs ->
// same work every call, graph-capture safe. L2-resident (1.2 MB); the main
// kernel loads A-fragments straight from here into VGPRs - no LDS staging.
__device__ __align__(16) ushort_t g_ws[(size_t)N_FRAGS * 512];

DEVINL ushort_t f2h_u(float v) { return __half_as_ushort(__float2half(v)); }

// ---------------------------------------------------------------------------
// Fragment element generator. Fragment (kt,nt): 512 f16; lane L (q=L>>4,
// cc=L&15) holds W[k = kt*32 + q*8 + j][n = nt*16 + cc], j=0..7, as 4 dwords.
// skip63 (layer-4 concat layout): logical k<63 -> row k, k==63 -> 0,
// k>63 -> row k-1. Out-of-range k/n -> 0.
// ---------------------------------------------------------------------------
DEVINL uint4 make_frag_qword(const float* __restrict__ W, int Kr, int Nr,
                             int skip63, int kt, int nt, int q, int cc)
{
    const int n = nt*16 + cc;
    uint32 pk[4];
    #pragma unroll
    for (int jj = 0; jj < 4; ++jj) {
        ushort_t h2[2];
        #pragma unroll
        for (int e = 0; e < 2; ++e) {
            const int k = kt*32 + q*8 + jj*2 + e;
            float v = 0.f;
            if (n < Nr) {
                if (skip63) {
                    if (k != 63) { const int rr = (k < 63) ? k : (k - 1); v = W[(size_t)rr*Nr + n]; }
                } else if (k < Kr) {
                    v = W[(size_t)k*Nr + n];
                }
            }
            h2[e] = f2h_u(v);
        }
        pk[jj] = (uint32)h2[0] | ((uint32)h2[1] << 16);
    }
    return make_uint4(pk[0], pk[1], pk[2], pk[3]);
}

// prep: fp32 weights -> f16 fragments in g_ws (once per launch)
__global__ __launch_bounds__(256) void prep_weights(
    const float* __restrict__ w0, const float* __restrict__ w1,
    const float* __restrict__ w2, const float* __restrict__ w3,
    const float* __restrict__ w4, const float* __restrict__ w5,
    const float* __restrict__ w6, const float* __restrict__ w7,
    const float* __restrict__ wf, const float* __restrict__ wsig,
    const float* __restrict__ wr1, const float* __restrict__ wr2)
{
    int gid  = blockIdx.x * 256 + threadIdx.x;
    int frag = gid >> 6;
    if (frag >= N_FRAGS) return;
    int lane = gid & 63;
    const int foff[13] = {0,32,160,288,416,576,704,832,960,1088,1096,1168,1172};
    const int NT[12]   = {16,16,16,16,16,16,16,16,16,1,8,1};
    const int KR[12]   = {63,256,256,256,319,256,256,256,256,256,283,128};
    const int NR[12]   = {256,256,256,256,256,256,256,256,256,1,128,3};
    const float* WP[12] = {w0,w1,w2,w3,w4,w5,w6,w7,wf,wsig,wr1,wr2};
    int t = 0;
    while (frag >= foff[t+1]) ++t;
    int fl = frag - foff[t];
    int nt = fl % NT[t];
    int kt = fl / NT[t];
    uint4 pk = make_frag_qword(WP[t], KR[t], NR[t], (t == 4) ? 1 : 0, kt, nt,
                               lane >> 4, lane & 15);
    *(uint4*)(g_ws + (size_t)frag*512 + lane*8) = pk;
}

// ---------------------------------------------------------------------------
// Layer: D[n][m] = sum_k W[k][n] * h[m][k]. A-operand fragments loaded
// DIRECTLY from global (L2-hot g_ws), depth-1 prefetched (long latency).
// B-operand activation rows read from LDS just-in-time (short latency; no
// double buffer -> keeps unified reg demand under the 3-block/CU cap, which
// round 4 showed matters: demand > cap => 250MB of scratch spill traffic).
// ---------------------------------------------------------------------------
template <int NT_W, int KT, int KT_SPLIT, int NTT>
DEVINL void run_layer(const ushort_t* __restrict__ wsrc,
                      const ushort_t* in0, int s0,
                      const ushort_t* in1, int s1,
                      int lane, int q, int cc, int nt_lo,
                      floatx4 (&acc)[4][NT_W])
{
    const floatx4 vzero = {0.f, 0.f, 0.f, 0.f};
    #pragma unroll
    for (int rt = 0; rt < 4; ++rt)
        #pragma unroll
        for (int nt = 0; nt < NT_W; ++nt)
            acc[rt][nt] = vzero;

    half8 afr[2][NT_W];

    auto loadA = [&](int kt, int buf) {
        const ushort_t* wb = wsrc + (size_t)(kt*NTT + nt_lo)*512 + lane*8;
        #pragma unroll
        for (int nt = 0; nt < NT_W; ++nt)
            afr[buf][nt] = *(const half8*)(wb + nt*512);
    };

    loadA(0, 0);
    #pragma unroll
    for (int kt = 0; kt < KT; ++kt) {
        const int cur = kt & 1;
        if (kt + 1 < KT) loadA(kt + 1, cur ^ 1);
        // just-in-time LDS B-fragment loads (transient registers)
        const ushort_t* src; int st, kk;
        if (kt < KT_SPLIT) { src = in0; st = s0; kk = kt*32; }
        else               { src = in1; st = s1; kk = (kt - KT_SPLIT)*32; }
        half8 bfr[4];
        #pragma unroll
        for (int rt = 0; rt < 4; ++rt)
            bfr[rt] = *(const half8*)(src + (rt*16 + cc)*st + kk + q*8);
        #pragma unroll
        for (int nt = 0; nt < NT_W; ++nt)
            #pragma unroll
            for (int rt = 0; rt < 4; ++rt)
                acc[rt][nt] = __builtin_amdgcn_mfma_f32_16x16x32_f16(
                    afr[cur][nt], bfr[rt], acc[rt][nt], 0, 0, 0);
    }
}

// epilogue: +bias, optional relu, pack to f16, 8B LDS store per (rt,nt)
// D layout: m = rt*16 + (lane&15), features n..n+3 = (nt_lo+nt)*16 + q*4 + reg
template <int NT_W, bool RELU>
DEVINL void epilogue_h(floatx4 (&acc)[4][NT_W], const float* __restrict__ bias,
                       int nt_lo, ushort_t* shh, int q, int cc)
{
    #pragma unroll
    for (int rt = 0; rt < 4; ++rt) {
        const int m = rt*16 + cc;
        #pragma unroll
        for (int nt = 0; nt < NT_W; ++nt) {
            const int n = (nt_lo + nt)*16 + q*4;
            floatx4 v = acc[rt][nt];
            const floatx4 bb = *(const floatx4*)(bias + n);
            v = v + bb;
            if (RELU) {
                v.x = fmaxf(v.x, 0.f); v.y = fmaxf(v.y, 0.f);
                v.z = fmaxf(v.z, 0.f); v.w = fmaxf(v.w, 0.f);
            }
            uint2 u;
            u.x = (uint32)f2h_u(v.x) | ((uint32)f2h_u(v.y) << 16);
            u.y = (uint32)f2h_u(v.z) | ((uint32)f2h_u(v.w) << 16);
            *(uint2*)(shh + (size_t)m*HSTR + n) = u;
        }
    }
}

// 3 blocks/CU: LDS 48.1KB, unified reg cap 168/lane.
__global__ __launch_bounds__(256, 3) void nerf_fused(
    const float* __restrict__ x,
    const float* __restrict__ b0, const float* __restrict__ b1,
    const float* __restrict__ b2, const float* __restrict__ b3,
    const float* __restrict__ b4, const float* __restrict__ b5,
    const float* __restrict__ b6, const float* __restrict__ b7,
    const float* __restrict__ bf, const float* __restrict__ bsig,
    const float* __restrict__ br1, const float* __restrict__ br2,
    float* __restrict__ out)
{
    __shared__ __align__(16) ushort_t shh[64*HSTR];   // activations, f16
    __shared__ __align__(16) ushort_t shx[64*XSTR];   // xyz posenc (63+pad)
    __shared__ __align__(16) ushort_t shd[64*DSTR];   // dir posenc (27+pad)

    const int tid  = threadIdx.x;
    const int wave = tid >> 6, lane = tid & 63;
    const int q = lane >> 4, cc = lane & 15;
    const int r0 = blockIdx.x * 64;
    const ushort_t* ws = g_ws;

    // ---- positional encoding (row = lane, job-set = wave) ----
    {
        const int r = lane;
        const float* xr = x + (size_t)(r0 + r)*6;
        for (int j = wave; j < 42; j += 4) {
            if (j < 30) {               // xyz: F=10, layout 3 + f*6 + s*3 + a
                int f = j/3, a = j%3;
                float v = xr[a] * (float)(1 << f);
                shx[r*XSTR + 3 + f*6 + a]     = f2h_u(sinf(v));
                shx[r*XSTR + 3 + f*6 + 3 + a] = f2h_u(cosf(v));
            } else {                    // dir: F=4
                int jj = j - 30, f = jj/3, a = jj%3;
                float v = xr[3+a] * (float)(1 << f);
                shd[r*DSTR + 3 + f*6 + a]     = f2h_u(sinf(v));
                shd[r*DSTR + 3 + f*6 + 3 + a] = f2h_u(cosf(v));
            }
        }
        if (wave == 0) {
            #pragma unroll
            for (int a = 0; a < 3; ++a) {
                shx[r*XSTR + a] = f2h_u(xr[a]);
                shd[r*DSTR + a] = f2h_u(xr[3+a]);
            }
            shx[r*XSTR + 63] = 0;                       // k-pad must be 0
            #pragma unroll
            for (int kq = 27; kq < 32; ++kq) shd[r*DSTR + kq] = 0;
        }
    }
    __syncthreads();

    const float* BS[8] = {b0,b1,b2,b3,b4,b5,b6,b7};
    const int WO[8] = {0,16384,81920,147456,212992,294912,360448,425984};
    const int nt_lo4 = wave * 4;

    floatx4 acc[4][4];

    // layer 0: 64(xyz) -> 256  (reads shx, writes shh: no pre-epi barrier needed)
    run_layer<4,2,2,16>(ws + WO[0], shx, XSTR, shx, XSTR, lane, q, cc, nt_lo4, acc);
    epilogue_h<4,true>(acc, b0, nt_lo4, shh, q, cc);
    __syncthreads();

    // layers 1..7 (layer 4 = skip-concat: 2 kt from xyz, 8 kt from h)
    #pragma unroll
    for (int l = 1; l < 8; ++l) {
        if (l == 4)
            run_layer<4,10,2,16>(ws + WO[4], shx, XSTR, shh, HSTR, lane, q, cc, nt_lo4, acc);
        else
            run_layer<4,8,8,16>(ws + WO[l], shh, HSTR, shh, HSTR, lane, q, cc, nt_lo4, acc);
        __syncthreads();   // all waves done reading shh before epilogue overwrites
        epilogue_h<4,true>(acc, BS[l], nt_lo4, shh, q, cc);
        __syncthreads();   // epilogue visible before next layer reads
    }

    // sigma head: global store only, no LDS writes -> no barriers
    {
        floatx4 sacc[4][1];
        run_layer<1,8,8,1>(ws + 557056, shh, HSTR, shh, HSTR, lane, q, cc, 0, sacc);
        if (wave == 0 && q == 0) {     // feature 0 lives in reg 0 of quad 0
            const float bs_ = bsig[0];
            #pragma unroll
            for (int rt = 0; rt < 4; ++rt)
                out[(size_t)(r0 + rt*16 + cc)*4 + 3] = sacc[rt][0].x + bs_;
        }
    }

    // final: 256 -> 256, NO relu (barrier also covers in-flight sigma reads)
    run_layer<4,8,8,16>(ws + 491520, shh, HSTR, shh, HSTR, lane, q, cc, nt_lo4, acc);
    __syncthreads();
    epilogue_h<4,false>(acc, bf, nt_lo4, shh, q, cc);
    __syncthreads();

    // rgb1: [final(256) | dir(27->32)] -> 128, relu
    {
        floatx4 racc[4][2];
        run_layer<2,9,8,8>(ws + 561152, shh, HSTR, shd, DSTR, lane, q, cc, wave*2, racc);
        __syncthreads();
        epilogue_h<2,true>(racc, br1, wave*2, shh, q, cc);
        __syncthreads();
    }

    // rgb2: 128 -> 3, sigmoid, store rgb (global store only)
    {
        floatx4 cacc[4][1];
        run_layer<1,4,4,1>(ws + 598016, shh, HSTR, shh, HSTR, lane, q, cc, 0, cacc);
        if (wave == 0 && q == 0) {
            const float c0 = br2[0], c1 = br2[1], c2 = br2[2];
            #pragma unroll
            for (int rt = 0; rt < 4; ++rt) {
                const size_t o = (size_t)(r0 + rt*16 + cc)*4;
                out[o+0] = 1.f/(1.f + expf(-(cacc[rt][0].x + c0)));
                out[o+1] = 1.f/(1.f + expf(-(cacc[rt][0].y + c1)));
                out[o+2] = 1.f/(1.f + expf(-(cacc[rt][0].z + c2)));
            }
        }
    }
}

extern "C" void kernel_launch(void* const* d_in, const int* in_sizes, int n_in,
                              void* d_out, int out_size, void* d_ws, size_t ws_size,
                              hipStream_t stream)
{
    const float* x  = (const float*)d_in[0];
    const float* w0 = (const float*)d_in[1];  const float* b0 = (const float*)d_in[2];
    const float* w1 = (const float*)d_in[3];  const float* b1 = (const float*)d_in[4];
    const float* w2 = (const float*)d_in[5];  const float* b2 = (const float*)d_in[6];
    const float* w3 = (const float*)d_in[7];  const float* b3 = (const float*)d_in[8];
    const float* w4 = (const float*)d_in[9];  const float* b4 = (const float*)d_in[10];
    const float* w5 = (const float*)d_in[11]; const float* b5 = (const float*)d_in[12];
    const float* w6 = (const float*)d_in[13]; const float* b6 = (const float*)d_in[14];
    const float* w7 = (const float*)d_in[15]; const float* b7 = (const float*)d_in[16];
    const float* wf = (const float*)d_in[17]; const float* bf = (const float*)d_in[18];
    const float* wsg= (const float*)d_in[19]; const float* bsg= (const float*)d_in[20];
    const float* wr1= (const float*)d_in[21]; const float* br1= (const float*)d_in[22];
    const float* wr2= (const float*)d_in[23]; const float* br2= (const float*)d_in[24];
    float* out = (float*)d_out;
    const int N = in_sizes[0] / 6;

    prep_weights<<<(N_FRAGS*64 + 255)/256, 256, 0, stream>>>(
        w0,w1,w2,w3,w4,w5,w6,w7,wf,wsg,wr1,wr2);
    nerf_fused<<<N/64, 256, 0, stream>>>(
        x, b0,b1,b2,b3,b4,b5,b6,b7, bf,bsg, br1,br2, out);
}

// Round 6
// 389.159 us; speedup vs baseline: 1.1004x; 1.1004x over previous
//
#include <hip/hip_runtime.h>
#include <hip/hip_fp16.h>
#include <stdint.h>

typedef unsigned int   uint32;
typedef unsigned short ushort_t;
typedef _Float16 half8   __attribute__((ext_vector_type(8)));
typedef float    floatx4 __attribute__((ext_vector_type(4)));

#define DEVINL __device__ __forceinline__

#define HSTR 264   // h buffer stride (256 + 8 pad), multiple of 8 for 16B-aligned b128
#define XSTR 72    // xyz-posenc stride (64 + 8 pad)
#define DSTR 40    // dir-posenc stride (32 + 8 pad)
#define N_FRAGS 1172            // total 1KB weight fragments

// Packed f16 weight fragments in module-owned device memory (d_ws is too small;
// round-1 showed OOB d_ws writes corrupt the harness's pristine copies).
// prep_weights rewrites this every launch from the restored fp32 inputs ->
// same work every call, graph-capture safe. L2-resident (1.2 MB); the main
// kernel loads A-fragments straight from here into VGPRs.
__device__ __align__(16) ushort_t g_ws[(size_t)N_FRAGS * 512];

DEVINL ushort_t f2h_u(float v) { return __half_as_ushort(__float2half(v)); }

// ---------------------------------------------------------------------------
// Fragment element generator. Fragment (kt,nt): 512 f16; lane L (q=L>>4,
// cc=L&15) holds W[k = kt*32 + q*8 + j][n = nt*16 + cc], j=0..7, as 4 dwords.
// skip63 (layer-4 concat layout): logical k<63 -> row k, k==63 -> 0,
// k>63 -> row k-1. Out-of-range k/n -> 0.
// ---------------------------------------------------------------------------
DEVINL uint4 make_frag_qword(const float* __restrict__ W, int Kr, int Nr,
                             int skip63, int kt, int nt, int q, int cc)
{
    const int n = nt*16 + cc;
    uint32 pk[4];
    #pragma unroll
    for (int jj = 0; jj < 4; ++jj) {
        ushort_t h2[2];
        #pragma unroll
        for (int e = 0; e < 2; ++e) {
            const int k = kt*32 + q*8 + jj*2 + e;
            float v = 0.f;
            if (n < Nr) {
                if (skip63) {
                    if (k != 63) { const int rr = (k < 63) ? k : (k - 1); v = W[(size_t)rr*Nr + n]; }
                } else if (k < Kr) {
                    v = W[(size_t)k*Nr + n];
                }
            }
            h2[e] = f2h_u(v);
        }
        pk[jj] = (uint32)h2[0] | ((uint32)h2[1] << 16);
    }
    return make_uint4(pk[0], pk[1], pk[2], pk[3]);
}

// prep: fp32 weights -> f16 fragments in g_ws (once per launch)
__global__ __launch_bounds__(256) void prep_weights(
    const float* __restrict__ w0, const float* __restrict__ w1,
    const float* __restrict__ w2, const float* __restrict__ w3,
    const float* __restrict__ w4, const float* __restrict__ w5,
    const float* __restrict__ w6, const float* __restrict__ w7,
    const float* __restrict__ wf, const float* __restrict__ wsig,
    const float* __restrict__ wr1, const float* __restrict__ wr2)
{
    int gid  = blockIdx.x * 256 + threadIdx.x;
    int frag = gid >> 6;
    if (frag >= N_FRAGS) return;
    int lane = gid & 63;
    const int foff[13] = {0,32,160,288,416,576,704,832,960,1088,1096,1168,1172};
    const int NT[12]   = {16,16,16,16,16,16,16,16,16,1,8,1};
    const int KR[12]   = {63,256,256,256,319,256,256,256,256,256,283,128};
    const int NR[12]   = {256,256,256,256,256,256,256,256,256,1,128,3};
    const float* WP[12] = {w0,w1,w2,w3,w4,w5,w6,w7,wf,wsig,wr1,wr2};
    int t = 0;
    while (frag >= foff[t+1]) ++t;
    int fl = frag - foff[t];
    int nt = fl % NT[t];
    int kt = fl / NT[t];
    uint4 pk = make_frag_qword(WP[t], KR[t], NR[t], (t == 4) ? 1 : 0, kt, nt,
                               lane >> 4, lane & 15);
    *(uint4*)(g_ws + (size_t)frag*512 + lane*8) = pk;
}

// ---------------------------------------------------------------------------
// Layer: D[n][m] = sum_k W[k][n] * h[m][k]. A-operand fragments loaded
// DIRECTLY from global (L2-hot g_ws), B-operand activation rows from LDS;
// both depth-1 software-pipelined. Reg demand ~180/wave; needs the 256-reg
// cap of __launch_bounds__(256,2) - at (256,3)'s 168 cap this spills to
// scratch (round 4/5: 183 MB of HBM spill writes, VGPR split 84+84=168).
// ---------------------------------------------------------------------------
template <int NT_W, int KT, int KT_SPLIT, int NTT>
DEVINL void run_layer(const ushort_t* __restrict__ wsrc,
                      const ushort_t* in0, int s0,
                      const ushort_t* in1, int s1,
                      int lane, int q, int cc, int nt_lo,
                      floatx4 (&acc)[4][NT_W])
{
    const floatx4 vzero = {0.f, 0.f, 0.f, 0.f};
    #pragma unroll
    for (int rt = 0; rt < 4; ++rt)
        #pragma unroll
        for (int nt = 0; nt < NT_W; ++nt)
            acc[rt][nt] = vzero;

    half8 bfr[2][4];
    half8 afr[2][NT_W];

    auto loadk = [&](int kt, int buf) {
        const ushort_t* src; int st, kk;
        if (kt < KT_SPLIT) { src = in0; st = s0; kk = kt*32; }
        else               { src = in1; st = s1; kk = (kt - KT_SPLIT)*32; }
        #pragma unroll
        for (int rt = 0; rt < 4; ++rt)
            bfr[buf][rt] = *(const half8*)(src + (rt*16 + cc)*st + kk + q*8);
        const ushort_t* wb = wsrc + (size_t)(kt*NTT + nt_lo)*512 + lane*8;
        #pragma unroll
        for (int nt = 0; nt < NT_W; ++nt)
            afr[buf][nt] = *(const half8*)(wb + nt*512);
    };

    loadk(0, 0);
    #pragma unroll
    for (int kt = 0; kt < KT; ++kt) {
        const int cur = kt & 1;
        if (kt + 1 < KT) loadk(kt + 1, cur ^ 1);
        #pragma unroll
        for (int nt = 0; nt < NT_W; ++nt)
            #pragma unroll
            for (int rt = 0; rt < 4; ++rt)
                acc[rt][nt] = __builtin_amdgcn_mfma_f32_16x16x32_f16(
                    afr[cur][nt], bfr[cur][rt], acc[rt][nt], 0, 0, 0);
    }
}

// epilogue: +bias, optional relu, pack to f16, 8B LDS store per (rt,nt)
// D layout: m = rt*16 + (lane&15), features n..n+3 = (nt_lo+nt)*16 + q*4 + reg
template <int NT_W, bool RELU>
DEVINL void epilogue_h(floatx4 (&acc)[4][NT_W], const float* __restrict__ bias,
                       int nt_lo, ushort_t* shh, int q, int cc)
{
    #pragma unroll
    for (int rt = 0; rt < 4; ++rt) {
        const int m = rt*16 + cc;
        #pragma unroll
        for (int nt = 0; nt < NT_W; ++nt) {
            const int n = (nt_lo + nt)*16 + q*4;
            floatx4 v = acc[rt][nt];
            const floatx4 bb = *(const floatx4*)(bias + n);
            v = v + bb;
            if (RELU) {
                v.x = fmaxf(v.x, 0.f); v.y = fmaxf(v.y, 0.f);
                v.z = fmaxf(v.z, 0.f); v.w = fmaxf(v.w, 0.f);
            }
            uint2 u;
            u.x = (uint32)f2h_u(v.x) | ((uint32)f2h_u(v.y) << 16);
            u.y = (uint32)f2h_u(v.z) | ((uint32)f2h_u(v.w) << 16);
            *(uint2*)(shh + (size_t)m*HSTR + n) = u;
        }
    }
}

// (256,2): 256-reg/wave cap -> no scratch spill; 2 blocks/CU (LDS 48.1KB).
__global__ __launch_bounds__(256, 2) void nerf_fused(
    const float* __restrict__ x,
    const float* __restrict__ b0, const float* __restrict__ b1,
    const float* __restrict__ b2, const float* __restrict__ b3,
    const float* __restrict__ b4, const float* __restrict__ b5,
    const float* __restrict__ b6, const float* __restrict__ b7,
    const float* __restrict__ bf, const float* __restrict__ bsig,
    const float* __restrict__ br1, const float* __restrict__ br2,
    float* __restrict__ out)
{
    __shared__ __align__(16) ushort_t shh[64*HSTR];   // activations, f16
    __shared__ __align__(16) ushort_t shx[64*XSTR];   // xyz posenc (63+pad)
    __shared__ __align__(16) ushort_t shd[64*DSTR];   // dir posenc (27+pad)

    const int tid  = threadIdx.x;
    const int wave = tid >> 6, lane = tid & 63;
    const int q = lane >> 4, cc = lane & 15;
    const int r0 = blockIdx.x * 64;
    const ushort_t* ws = g_ws;

    // ---- positional encoding (row = lane, job-set = wave) ----
    {
        const int r = lane;
        const float* xr = x + (size_t)(r0 + r)*6;
        for (int j = wave; j < 42; j += 4) {
            if (j < 30) {               // xyz: F=10, layout 3 + f*6 + s*3 + a
                int f = j/3, a = j%3;
                float v = xr[a] * (float)(1 << f);
                shx[r*XSTR + 3 + f*6 + a]     = f2h_u(sinf(v));
                shx[r*XSTR + 3 + f*6 + 3 + a] = f2h_u(cosf(v));
            } else {                    // dir: F=4
                int jj = j - 30, f = jj/3, a = jj%3;
                float v = xr[3+a] * (float)(1 << f);
                shd[r*DSTR + 3 + f*6 + a]     = f2h_u(sinf(v));
                shd[r*DSTR + 3 + f*6 + 3 + a] = f2h_u(cosf(v));
            }
        }
        if (wave == 0) {
            #pragma unroll
            for (int a = 0; a < 3; ++a) {
                shx[r*XSTR + a] = f2h_u(xr[a]);
                shd[r*DSTR + a] = f2h_u(xr[3+a]);
            }
            shx[r*XSTR + 63] = 0;                       // k-pad must be 0
            #pragma unroll
            for (int kq = 27; kq < 32; ++kq) shd[r*DSTR + kq] = 0;
        }
    }
    __syncthreads();

    const float* BS[8] = {b0,b1,b2,b3,b4,b5,b6,b7};
    const int WO[8] = {0,16384,81920,147456,212992,294912,360448,425984};
    const int nt_lo4 = wave * 4;

    floatx4 acc[4][4];

    // layer 0: 64(xyz) -> 256  (reads shx, writes shh: no pre-epi barrier needed)
    run_layer<4,2,2,16>(ws + WO[0], shx, XSTR, shx, XSTR, lane, q, cc, nt_lo4, acc);
    epilogue_h<4,true>(acc, b0, nt_lo4, shh, q, cc);
    __syncthreads();

    // layers 1..7 (layer 4 = skip-concat: 2 kt from xyz, 8 kt from h)
    #pragma unroll
    for (int l = 1; l < 8; ++l) {
        if (l == 4)
            run_layer<4,10,2,16>(ws + WO[4], shx, XSTR, shh, HSTR, lane, q, cc, nt_lo4, acc);
        else
            run_layer<4,8,8,16>(ws + WO[l], shh, HSTR, shh, HSTR, lane, q, cc, nt_lo4, acc);
        __syncthreads();   // all waves done reading shh before epilogue overwrites
        epilogue_h<4,true>(acc, BS[l], nt_lo4, shh, q, cc);
        __syncthreads();   // epilogue visible before next layer reads
    }

    // sigma head: wave 0 only (barrier-free region; others' result was unused)
    if (wave == 0) {
        floatx4 sacc[4][1];
        run_layer<1,8,8,1>(ws + 557056, shh, HSTR, shh, HSTR, lane, q, cc, 0, sacc);
        if (q == 0) {                  // feature 0 lives in reg 0 of quad 0
            const float bs_ = bsig[0];
            #pragma unroll
            for (int rt = 0; rt < 4; ++rt)
                out[(size_t)(r0 + rt*16 + cc)*4 + 3] = sacc[rt][0].x + bs_;
        }
    }

    // final: 256 -> 256, NO relu (barrier also covers in-flight sigma reads)
    run_layer<4,8,8,16>(ws + 491520, shh, HSTR, shh, HSTR, lane, q, cc, nt_lo4, acc);
    __syncthreads();
    epilogue_h<4,false>(acc, bf, nt_lo4, shh, q, cc);
    __syncthreads();

    // rgb1: [final(256) | dir(27->32)] -> 128, relu
    {
        floatx4 racc[4][2];
        run_layer<2,9,8,8>(ws + 561152, shh, HSTR, shd, DSTR, lane, q, cc, wave*2, racc);
        __syncthreads();
        epilogue_h<2,true>(racc, br1, wave*2, shh, q, cc);
        __syncthreads();
    }

    // rgb2: 128 -> 3, sigmoid, store rgb (wave 0 only, barrier-free region)
    if (wave == 0) {
        floatx4 cacc[4][1];
        run_layer<1,4,4,1>(ws + 598016, shh, HSTR, shh, HSTR, lane, q, cc, 0, cacc);
        if (q == 0) {
            const float c0 = br2[0], c1 = br2[1], c2 = br2[2];
            #pragma unroll
            for (int rt = 0; rt < 4; ++rt) {
                const size_t o = (size_t)(r0 + rt*16 + cc)*4;
                out[o+0] = 1.f/(1.f + expf(-(cacc[rt][0].x + c0)));
                out[o+1] = 1.f/(1.f + expf(-(cacc[rt][0].y + c1)));
                out[o+2] = 1.f/(1.f + expf(-(cacc[rt][0].z + c2)));
            }
        }
    }
}

extern "C" void kernel_launch(void* const* d_in, const int* in_sizes, int n_in,
                              void* d_out, int out_size, void* d_ws, size_t ws_size,
                              hipStream_t stream)
{
    const float* x  = (const float*)d_in[0];
    const float* w0 = (const float*)d_in[1];  const float* b0 = (const float*)d_in[2];
    const float* w1 = (const float*)d_in[3];  const float* b1 = (const float*)d_in[4];
    const float* w2 = (const float*)d_in[5];  const float* b2 = (const float*)d_in[6];
    const float* w3 = (const float*)d_in[7];  const float* b3 = (const float*)d_in[8];
    const float* w4 = (const float*)d_in[9];  const float* b4 = (const float*)d_in[10];
    const float* w5 = (const float*)d_in[11]; const float* b5 = (const float*)d_in[12];
    const float* w6 = (const float*)d_in[13]; const float* b6 = (const float*)d_in[14];
    const float* w7 = (const float*)d_in[15]; const float* b7 = (const float*)d_in[16];
    const float* wf = (const float*)d_in[17]; const float* bf = (const float*)d_in[18];
    const float* wsg= (const float*)d_in[19]; const float* bsg= (const float*)d_in[20];
    const float* wr1= (const float*)d_in[21]; const float* br1= (const float*)d_in[22];
    const float* wr2= (const float*)d_in[23]; const float* br2= (const float*)d_in[24];
    float* out = (float*)d_out;
    const int N = in_sizes[0] / 6;

    prep_weights<<<(N_FRAGS*64 + 255)/256, 256, 0, stream>>>(
        w0,w1,w2,w3,w4,w5,w6,w7,wf,wsg,wr1,wr2);
    nerf_fused<<<N/64, 256, 0, stream>>>(
        x, b0,b1,b2,b3,b4,b5,b6,b7, bf,bsg, br1,br2, out);
}